// Round 5
// baseline (486.488 us; speedup 1.0000x reference)
//
#include <hip/hip_runtime.h>
#include <hip/hip_bf16.h>
#include <stdint.h>

// LinearDiscriminator: [T,B,H] fp32 -> MLP(1024->100->10->1) -> logsigmoid
// -> masked sum over T -> exp -> [B] fp32.  T=2048 B=32 H=1024.
// R5: ZERO barriers in the K-loop. Each wave is fully independent:
//  - owns M=32 rows, a private double-buffered LDS A-tile (no cross-wave dep)
//  - W1 fragments read directly from fragment-packed global (coalesced 1KB/inst,
//    L1/L2-resident) -- no W1 staging at all
//  - A loads register-prefetched one chunk ahead (ping-pong), row-predicated
//  - waves with t >= max(lengths) skip the K-loop entirely
// Only 2 block barriers total (W2 visibility, final partial reduce).

#define H_DIM  1024
#define L1_DIM 100
#define L2_DIM 10
#define NPART  512               // 512 blocks x 4 waves, M=32 rows/wave

#define W1P_ELEMS (112 * 1024)   // fragment-packed bf16
#define W2P_ELEMS (16 * 128)
#define PART_OFF_BYTES ((W1P_ELEMS + W2P_ELEMS) * 2)

// LDS: per-wave A region w*8704 (two 4352B buffers; reused as ldsH after loop)
#define APITCH  136              // bytes/row: 68 shorts (64 data + 4 pad)
#define ABUFSZ  4352             // 32 rows * 136
#define W2_OFF  34816            // [16][136 shorts] = 4352 B
#define PRT_OFF 39168            // float[4][32] = 512 B
#define LDS_TOTAL 39680

typedef float v4f __attribute__((ext_vector_type(4)));
typedef short s8  __attribute__((ext_vector_type(8)));
typedef short s4v __attribute__((ext_vector_type(4)));

static __device__ __forceinline__ unsigned short f2bf(float f) {
    unsigned int u = __float_as_uint(f);
    u += 0x7fffu + ((u >> 16) & 1u);
    return (unsigned short)(u >> 16);
}

static __device__ __forceinline__ s4v pack4(float4 f) {
    union { s4v v; __hip_bfloat162 h[2]; } u;
    u.h[0] = __float22bfloat162_rn(make_float2(f.x, f.y));
    u.h[1] = __float22bfloat162_rn(make_float2(f.z, f.w));
    return u.v;
}

// ---------------- kernel 0: pack W1 into fragment order, pad W2 ----------------
// w1p slot s = kc*896 + (ks*7+nt)*64 + lane (lane = q*16+m):
//   holds W1bf[nt*16+m][kc*64+ks*32+q*8 .. +7]
__global__ void convert_weights(const float* __restrict__ W1,
                                const float* __restrict__ W2,
                                unsigned short* __restrict__ wsb) {
    int s = blockIdx.x * 256 + threadIdx.x;
    union { uint4 u; unsigned short h[8]; } o;
    if (s < 14336) {
        int lane = s & 63, rest = s >> 6;     // rest = kc*14 + ks*7 + nt
        int nt = rest % 7, ksc = rest / 7;    // ksc = kc*2 + ks
        int m = lane & 15, q = lane >> 4;
        int row = nt * 16 + m;
        int col = ksc * 32 + q * 8;
        if (row < L1_DIM) {
            const float* src = W1 + row * H_DIM + col;
#pragma unroll
            for (int e = 0; e < 8; ++e) o.h[e] = f2bf(src[e]);
        } else {
            o.u = make_uint4(0u, 0u, 0u, 0u);
        }
        *(uint4*)(wsb + s * 8) = o.u;
    } else if (s < 14336 + 256) {
        int j = s - 14336;                    // W2 padded [16][128]
        int r = j >> 4, c = (j & 15) * 8;
#pragma unroll
        for (int e = 0; e < 8; ++e) {
            int cc = c + e;
            o.h[e] = (r < L2_DIM && cc < L1_DIM) ? f2bf(W2[r * L1_DIM + cc]) : 0;
        }
        *(uint4*)(wsb + W1P_ELEMS + j * 8) = o.u;
    }
}

// ---------------- kernel 1: main fused MLP ----------------
__global__ __launch_bounds__(256, 2) void mlp_main(
    const float* __restrict__ enc,      // [T][B][H] fp32
    const int*   __restrict__ lenp,     // int32 or int64 (runtime-detected)
    const float* __restrict__ b1,
    const float* __restrict__ b2,
    const float* __restrict__ W3,
    const float* __restrict__ b3,
    const unsigned short* __restrict__ w1p,  // fragment-packed bf16
    const unsigned short* __restrict__ w2p,  // bf16 [16][128]
    float* __restrict__ partials)            // fp32 [32][NPART]
{
    __shared__ __align__(16) unsigned char smem[LDS_TOTAL];

    const int tid  = threadIdx.x;
    const int blk  = blockIdx.x;
    const int lane = tid & 63;
    const int w    = tid >> 6;
    const int m    = lane & 15;
    const int q    = lane >> 4;

    const bool is64 = (lenp[1] == 0);  // lengths >= 1: int32 word1 != 0

    int maxlen = 0;
    for (int i = 0; i < 32; ++i) {
        int L = is64 ? lenp[2 * i] : lenp[i];
        maxlen = max(maxlen, L);
    }
    if (4 * blk >= maxlen) {
        if (tid < 32) partials[tid * NPART + blk] = 0.0f;
        return;
    }

    // stage W2 -> LDS [16][136 shorts] (visible after the post-loop barrier)
    {
        int r = tid >> 4, c = (tid & 15) * 8;
        *(uint4*)(smem + W2_OFF + r * 272 + c * 2) = *(const uint4*)(w2p + r * 128 + c);
    }

    // wave identity: t = 4*blk + w; rows (t, b=0..31)
    const int t = 4 * blk + w;
    const bool waveActive = (t < maxlen);
    const int wbase = w * 2 * ABUFSZ;          // per-wave LDS region

    // producer: inst j covers rows 4j+(lane>>4), cols (lane&15)*4 within chunk
    int plen[8];
#pragma unroll
    for (int j = 0; j < 8; ++j) {
        int b_ = 4 * j + (lane >> 4);
        plen[j] = is64 ? lenp[2 * b_] : lenp[b_];
    }
    const float* abase = enc + (size_t)(blk * 128 + w * 32 + (lane >> 4)) * H_DIM
                         + (lane & 15) * 4;
    const int lwb = (lane >> 4) * APITCH + (lane & 15) * 8;   // LDS write base
    const unsigned short* wlane = w1p + lane * 8;

    // epilogue constants
    float b1v[7];
#pragma unroll
    for (int nt = 0; nt < 7; ++nt) {
        int n = nt * 16 + m;
        b1v[nt] = (n < L1_DIM) ? b1[n] : 0.0f;
    }
    const float b2v = (m < L2_DIM) ? b2[m] : 0.0f;
    const float w3v = (m < L2_DIM) ? W3[m] : 0.0f;
    const float b3s = b3[0];

    v4f acc0[7], acc1[7];
#pragma unroll
    for (int nt = 0; nt < 7; ++nt) { acc0[nt] = (v4f)0.0f; acc1[nt] = (v4f)0.0f; }

    const float4 z4c = make_float4(0.f, 0.f, 0.f, 0.f);

#define LOADA(AR, kc)                                                        \
    {                                                                        \
        _Pragma("unroll")                                                    \
        for (int j = 0; j < 8; ++j)                                          \
            AR[j] = (t < plen[j]) ? *(const float4*)(abase + j * 4096 + (kc) * 64) \
                                  : z4c;                                     \
    }

#define WRITEA(BUF, AR)                                                      \
    {                                                                        \
        _Pragma("unroll")                                                    \
        for (int j = 0; j < 8; ++j)                                          \
            *(s4v*)(smem + (BUF) + lwb + j * (4 * APITCH)) = pack4(AR[j]);   \
    }

    // A-fragment read from private LDS tile: rows f*16+m, cols ks*32+q*8
#define RDFRAG(dst, BUF, f, ks)                                              \
    {                                                                        \
        const unsigned char* p_ = smem + (BUF) + ((f) * 16 + m) * APITCH     \
                                  + (ks) * 64 + q * 16;                      \
        s4v lo_ = *(const s4v*)p_;                                           \
        s4v hi_ = *(const s4v*)(p_ + 8);                                     \
        dst[0] = lo_[0]; dst[1] = lo_[1]; dst[2] = lo_[2]; dst[3] = lo_[3];  \
        dst[4] = hi_[0]; dst[5] = hi_[1]; dst[6] = hi_[2]; dst[7] = hi_[3];  \
    }

#define COMPUTE(kc, BUF)                                                     \
    {                                                                        \
        _Pragma("unroll")                                                    \
        for (int ks = 0; ks < 2; ++ks) {                                     \
            s8 af0, af1;                                                     \
            RDFRAG(af0, BUF, 0, ks);                                         \
            RDFRAG(af1, BUF, 1, ks);                                         \
            _Pragma("unroll")                                                \
            for (int nt = 0; nt < 7; ++nt) {                                 \
                s8 bf = *(const s8*)(wlane + ((kc) * 14 + ks * 7 + nt) * 512); \
                acc0[nt] = __builtin_amdgcn_mfma_f32_16x16x32_bf16(          \
                    af0, bf, acc0[nt], 0, 0, 0);                             \
                acc1[nt] = __builtin_amdgcn_mfma_f32_16x16x32_bf16(          \
                    af1, bf, acc1[nt], 0, 0, 0);                             \
            }                                                                \
        }                                                                    \
    }

    if (waveActive) {
        const int bufA = wbase, bufB = wbase + ABUFSZ;
        float4 arA[8], arB[8];
        LOADA(arA, 0)
        WRITEA(bufA, arA)
#pragma unroll
        for (int kc2 = 0; kc2 < 8; ++kc2) {
            const int kc = kc2 * 2;
            LOADA(arB, kc + 1)
            COMPUTE(kc, bufA)
            WRITEA(bufB, arB)
            if (kc2 < 7) LOADA(arA, kc + 2)
            COMPUTE(kc + 1, bufB)
            if (kc2 < 7) WRITEA(bufA, arA)
        }
    }

#undef COMPUTE
#undef RDFRAG
#undef WRITEA
#undef LOADA

    __syncthreads();   // W2 staging visible to all waves; A-tiles now reusable

    // ---- h1 = relu(acc + b1) -> ldsH (own wave region, pitch 272B, 32 rows) ----
    unsigned short* ldsH = (unsigned short*)(smem + wbase);
#pragma unroll
    for (int f = 0; f < 2; ++f) {
#pragma unroll
        for (int nt = 0; nt < 7; ++nt) {
#pragma unroll
            for (int reg = 0; reg < 4; ++reg) {
                int row = f * 16 + q * 4 + reg;
                int col = nt * 16 + m;
                float a = f ? acc1[nt][reg] : acc0[nt][reg];
                ldsH[row * 136 + col] = f2bf(fmaxf(a + b1v[nt], 0.0f));
            }
        }
    }
    // zero K-pad cols 112..127 (own rows; one b128 per lane)
    {
        int row = lane >> 1;
        uint4 z; z.x = z.y = z.z = z.w = 0u;
        *(uint4*)(ldsH + row * 136 + 112 + (lane & 1) * 8) = z;
    }

    // ---- layer-2 MFMA: M=32 (own rows) x N=16 over K=128 ----
    v4f acc2[2];
    acc2[0] = (v4f)0.0f; acc2[1] = (v4f)0.0f;
#pragma unroll
    for (int ks2 = 0; ks2 < 4; ++ks2) {
        s8 bw = *(const s8*)(smem + W2_OFF + m * 272 + (ks2 * 32 + q * 8) * 2);
#pragma unroll
        for (int f = 0; f < 2; ++f) {
            s8 ah = *(const s8*)((const unsigned char*)ldsH
                                 + (f * 16 + m) * 272 + (ks2 * 32 + q * 8) * 2);
            acc2[f] = __builtin_amdgcn_mfma_f32_16x16x32_bf16(ah, bw, acc2[f], 0, 0, 0);
        }
    }

    // ---- layer 3 + logsigmoid + per-t mask ----
    float* ldsPart = (float*)(smem + PRT_OFF);   // [4][32]
#pragma unroll
    for (int f = 0; f < 2; ++f) {
        v4f zv;
#pragma unroll
        for (int reg = 0; reg < 4; ++reg)
            zv[reg] = fmaxf(acc2[f][reg] + b2v, 0.0f) * w3v;
#pragma unroll
        for (int msk = 1; msk < 16; msk <<= 1) {
#pragma unroll
            for (int reg = 0; reg < 4; ++reg)
                zv[reg] += __shfl_xor(zv[reg], msk, 16);
        }
        if (m == 0) {
#pragma unroll
            for (int reg = 0; reg < 4; ++reg) {
                int b = f * 16 + q * 4 + reg;     // local row == batch index
                int lenB = is64 ? lenp[2 * b] : lenp[b];
                float logit = zv[reg] + b3s;
                float logp  = fminf(logit, 0.0f) - log1pf(__expf(-fabsf(logit)));
                ldsPart[w * 32 + b] = (t < lenB) ? logp : 0.0f;
            }
        }
    }
    __syncthreads();
    if (tid < 32)
        partials[tid * NPART + blk] =
            (ldsPart[tid] + ldsPart[32 + tid]) + (ldsPart[64 + tid] + ldsPart[96 + tid]);
}

// ---------------- kernel 2: reduce + exp ----------------
__global__ void finalize(const float* __restrict__ partials,
                         float* __restrict__ out) {
    const int b = blockIdx.x;
    const int tid = threadIdx.x;
    float s = 0.0f;
    for (int i = tid; i < NPART; i += 256) s += partials[b * NPART + i];
#pragma unroll
    for (int off = 32; off > 0; off >>= 1) s += __shfl_down(s, off, 64);
    __shared__ float red[4];
    if ((tid & 63) == 0) red[tid >> 6] = s;
    __syncthreads();
    if (tid == 0) out[b] = expf(red[0] + red[1] + red[2] + red[3]);
}

extern "C" void kernel_launch(void* const* d_in, const int* in_sizes, int n_in,
                              void* d_out, int out_size, void* d_ws, size_t ws_size,
                              hipStream_t stream) {
    const float* enc = (const float*)d_in[0];
    const int*   len = (const int*)d_in[1];
    const float* W1  = (const float*)d_in[2];
    const float* b1  = (const float*)d_in[3];
    const float* W2  = (const float*)d_in[4];
    const float* b2  = (const float*)d_in[5];
    const float* W3  = (const float*)d_in[6];
    const float* b3  = (const float*)d_in[7];

    unsigned short* wsb = (unsigned short*)d_ws;
    float* partials = (float*)((char*)d_ws + PART_OFF_BYTES);
    float* out = (float*)d_out;

    convert_weights<<<57, 256, 0, stream>>>(W1, W2, wsb);
    mlp_main<<<NPART, 256, 0, stream>>>(enc, len, b1, b2, W3, b3,
                                        wsb, wsb + W1P_ELEMS, partials);
    finalize<<<32, 256, 0, stream>>>(partials, out);
}

// Round 6
// 386.518 us; speedup vs baseline: 1.2586x; 1.2586x over previous
//
#include <hip/hip_runtime.h>
#include <hip/hip_bf16.h>
#include <stdint.h>

// LinearDiscriminator: [T,B,H] fp32 -> MLP(1024->100->10->1) -> logsigmoid
// -> masked sum over T -> exp -> [B] fp32.  T=2048 B=32 H=1024.
// R6: occupancy-first (latency-bound per R1..R5 evidence).
//  - 1024 blocks, M=16 rows/wave (R1 geometry, fastest so far)
//  - LDS 28.9 KB -> 5 blocks = 20 waves/CU (launch_bounds(256,5))
//  - W1 fragment-packed in d_ws; staged per BK=64 chunk via lane-linear
//    global_load_lds into a double buffer; ONE barrier per chunk
//  - A (encoder) direct from global, register ping-pong, row-predicated
//  - W2 fragments read directly from packed global (no LDS), ldsH aliases dbuf

#define H_DIM  1024
#define L1_DIM 100
#define L2_DIM 10
#define NBLK   1024              // mlp_main grid: 64 rows/block

#define W1P_ELEMS (112 * 1024)   // fragment-packed bf16
#define W2P_ELEMS (4 * 64 * 8)   // 2048: fragment-packed W2 [ks2][lane][8]
#define PART_OFF_BYTES ((W1P_ELEMS + W2P_ELEMS) * 2)

#define CHUNK_B 14336            // one W1 chunk (112x64 bf16) fragment-packed
#define PRT_OFF 28672            // float[2][32]
#define LDS_TOTAL 28928          // 28672 dbuf (aliased by ldsH[4][4352]) + 256

typedef float v4f __attribute__((ext_vector_type(4)));
typedef short s8  __attribute__((ext_vector_type(8)));

static __device__ __forceinline__ unsigned short f2bf(float f) {
    unsigned int u = __float_as_uint(f);
    u += 0x7fffu + ((u >> 16) & 1u);
    return (unsigned short)(u >> 16);
}

static __device__ __forceinline__ s8 pack8(float4 a, float4 b) {
    union { s8 v; __hip_bfloat162 h[4]; } u;
    u.h[0] = __float22bfloat162_rn(make_float2(a.x, a.y));
    u.h[1] = __float22bfloat162_rn(make_float2(a.z, a.w));
    u.h[2] = __float22bfloat162_rn(make_float2(b.x, b.y));
    u.h[3] = __float22bfloat162_rn(make_float2(b.z, b.w));
    return u.v;
}

// ---------------- kernel 0: pack W1 + W2 into MFMA fragment order ----------------
// W1 slot s = kc*896 + (ks*7+nt)*64 + lane: W1bf[nt*16+(lane&15)][kc*64+ks*32+(lane>>4)*8+e]
// W2 slot j = ks2*64 + lane:                W2bf[lane&15][ks2*32+(lane>>4)*8+e]
__global__ void convert_weights(const float* __restrict__ W1,
                                const float* __restrict__ W2,
                                unsigned short* __restrict__ wsb) {
    int s = blockIdx.x * 256 + threadIdx.x;
    union { uint4 u; unsigned short h[8]; } o;
    if (s < 14336) {
        int lane = s & 63, rest = s >> 6;     // rest = kc*14 + ks*7 + nt
        int nt = rest % 7, ksc = rest / 7;    // ksc = kc*2 + ks
        int m = lane & 15, q = lane >> 4;
        int row = nt * 16 + m;
        int col = ksc * 32 + q * 8;
        if (row < L1_DIM) {
            const float* src = W1 + row * H_DIM + col;
#pragma unroll
            for (int e = 0; e < 8; ++e) o.h[e] = f2bf(src[e]);
        } else {
            o.u = make_uint4(0u, 0u, 0u, 0u);
        }
        *(uint4*)(wsb + s * 8) = o.u;
    } else if (s < 14336 + 256) {
        int j = s - 14336;
        int lane = j & 63, ks2 = j >> 6;
        int m = lane & 15, q = lane >> 4;
#pragma unroll
        for (int e = 0; e < 8; ++e) {
            int c = ks2 * 32 + q * 8 + e;
            o.h[e] = (m < L2_DIM && c < L1_DIM) ? f2bf(W2[m * L1_DIM + c]) : 0;
        }
        *(uint4*)(wsb + W1P_ELEMS + j * 8) = o.u;
    }
}

// ---------------- kernel 1: main fused MLP ----------------
__global__ __launch_bounds__(256, 5) void mlp_main(
    const float* __restrict__ enc,      // [T][B][H] fp32
    const int*   __restrict__ lenp,     // int32 or int64 (runtime-detected)
    const float* __restrict__ b1,
    const float* __restrict__ b2,
    const float* __restrict__ W3,
    const float* __restrict__ b3,
    const unsigned short* __restrict__ w1p,  // fragment-packed bf16
    const unsigned short* __restrict__ w2p,  // fragment-packed bf16 (2048)
    float* __restrict__ partials)            // fp32 [32][NBLK]
{
    __shared__ __align__(16) unsigned char smem[LDS_TOTAL];

    const int tid  = threadIdx.x;
    const int blk  = blockIdx.x;
    const int lane = tid & 63;
    const int w    = tid >> 6;
    const int m    = lane & 15;
    const int q    = lane >> 4;

    const bool is64 = (lenp[1] == 0);  // lengths >= 1: int32 word1 != 0

    // wave-parallel maxlen (each b read by 2 lanes; xor-shuffle reduce)
    int bb = lane & 31;
    int maxlen = is64 ? lenp[2 * bb] : lenp[bb];
#pragma unroll
    for (int off = 1; off <= 16; off <<= 1)
        maxlen = max(maxlen, __shfl_xor(maxlen, off, 64));

    if (2 * blk >= maxlen) {
        if (tid < 32) partials[tid * NBLK + blk] = 0.0f;
        return;
    }

    // rows: wave w -> t = 2blk + (w>>1), b = (w&1)*16 + m
    const int tA = 2 * blk + (w >> 1);
    const int bA = ((w & 1) << 4) + m;
    const int lenA = is64 ? lenp[2 * bA] : lenp[bA];
    const bool predA = (tA < lenA);
    const bool waveActive = (tA < maxlen);

    // epilogue constants
    float b1v[7];
#pragma unroll
    for (int nt = 0; nt < 7; ++nt) {
        int n = nt * 16 + m;
        b1v[nt] = (n < L1_DIM) ? b1[n] : 0.0f;
    }
    const float b2v = (m < L2_DIM) ? b2[m] : 0.0f;
    const float w3v = (m < L2_DIM) ? W3[m] : 0.0f;
    const float b3s = b3[0];

    // A pointer: row blk*64 + w*16 + m, cols q*8 ...
    const float* ap = enc + (size_t)(blk * 64 + w * 16 + m) * H_DIM + q * 8;

    v4f acc[7];
#pragma unroll
    for (int nt = 0; nt < 7; ++nt) acc[nt] = (v4f)0.0f;

    const float4 z4c = make_float4(0.f, 0.f, 0.f, 0.f);

// stage W1 chunk kc into LDS base (896 x 16B slots, lane-linear, async)
#define STAGE(kc, BASE)                                                      \
    {                                                                        \
        _Pragma("unroll")                                                    \
        for (int it = 0; it < 4; ++it) {                                     \
            int j = it * 256 + tid;                                          \
            if (it < 3 || tid < 128) {                                       \
                __builtin_amdgcn_global_load_lds(                            \
                    (const __attribute__((address_space(1))) unsigned int*)  \
                        (w1p + (size_t)(kc) * 7168 + j * 8),                 \
                    (__attribute__((address_space(3))) unsigned int*)        \
                        (smem + (BASE) + (j & ~63) * 16),                    \
                    16, 0, 0);                                               \
            }                                                                \
        }                                                                    \
    }

#define LOADA(R0, R1, R2, R3, kc)                                            \
    {                                                                        \
        const float* a_ = ap + (kc) * 64;                                    \
        R0 = predA ? *(const float4*)(a_)      : z4c;                        \
        R1 = predA ? *(const float4*)(a_ + 4)  : z4c;                        \
        R2 = predA ? *(const float4*)(a_ + 32) : z4c;                        \
        R3 = predA ? *(const float4*)(a_ + 36) : z4c;                        \
    }

#define COMPUTE(RD, A0, A1, A2, A3)                                          \
    if (waveActive) {                                                        \
        s8 af = pack8(A0, A1);                                               \
        _Pragma("unroll")                                                    \
        for (int nt = 0; nt < 7; ++nt) {                                     \
            s8 bf = *(const s8*)(smem + (RD) + (nt * 64 + lane) * 16);       \
            acc[nt] = __builtin_amdgcn_mfma_f32_16x16x32_bf16(               \
                af, bf, acc[nt], 0, 0, 0);                                   \
        }                                                                    \
        af = pack8(A2, A3);                                                  \
        _Pragma("unroll")                                                    \
        for (int nt = 0; nt < 7; ++nt) {                                     \
            s8 bf = *(const s8*)(smem + (RD) + ((7 + nt) * 64 + lane) * 16); \
            acc[nt] = __builtin_amdgcn_mfma_f32_16x16x32_bf16(               \
                af, bf, acc[nt], 0, 0, 0);                                   \
        }                                                                    \
    }

    float4 pA0, pA1, pA2, pA3, nA0, nA1, nA2, nA3;
    STAGE(0, 0)
    LOADA(pA0, pA1, pA2, pA3, 0)
    __syncthreads();

#define KBODY(kc, RD, WR)                                                    \
    {                                                                        \
        if ((kc) < 15) {                                                     \
            STAGE((kc) + 1, WR)                                              \
            LOADA(nA0, nA1, nA2, nA3, (kc) + 1)                              \
        }                                                                    \
        COMPUTE(RD, pA0, pA1, pA2, pA3)                                      \
        pA0 = nA0; pA1 = nA1; pA2 = nA2; pA3 = nA3;                          \
        __syncthreads();                                                     \
    }

    KBODY(0,  0, CHUNK_B)      KBODY(1,  CHUNK_B, 0)
    KBODY(2,  0, CHUNK_B)      KBODY(3,  CHUNK_B, 0)
    KBODY(4,  0, CHUNK_B)      KBODY(5,  CHUNK_B, 0)
    KBODY(6,  0, CHUNK_B)      KBODY(7,  CHUNK_B, 0)
    KBODY(8,  0, CHUNK_B)      KBODY(9,  CHUNK_B, 0)
    KBODY(10, 0, CHUNK_B)      KBODY(11, CHUNK_B, 0)
    KBODY(12, 0, CHUNK_B)      KBODY(13, CHUNK_B, 0)
    KBODY(14, 0, CHUNK_B)      KBODY(15, CHUNK_B, 0)

#undef KBODY
#undef COMPUTE
#undef LOADA
#undef STAGE

    // ---- h1 = relu(acc+b1) -> per-wave ldsH [16][136 shorts] (aliases dbuf) ----
    unsigned short* ldsH = (unsigned short*)(smem + w * 4352);
#pragma unroll
    for (int nt = 0; nt < 7; ++nt) {
#pragma unroll
        for (int reg = 0; reg < 4; ++reg) {
            ldsH[(q * 4 + reg) * 136 + nt * 16 + m] =
                f2bf(fmaxf(acc[nt][reg] + b1v[nt], 0.0f));
        }
    }
    // zero K-pad cols 112..127 (16 rows x 16 cols; lanes 0..31, one uint4 each)
    if (lane < 32) {
        uint4 z; z.x = z.y = z.z = z.w = 0u;
        *(uint4*)(ldsH + (lane >> 1) * 136 + 112 + (lane & 1) * 8) = z;
    }
    // wave-local producer/consumer: compiler lgkmcnt ordering suffices

    // ---- layer-2 MFMA: M=16 (wave rows) x N=16 over K=128; W2 frags from global ----
    v4f acc2 = (v4f)0.0f;
#pragma unroll
    for (int ks2 = 0; ks2 < 4; ++ks2) {
        s8 bw = *(const s8*)(w2p + (ks2 * 64 + lane) * 8);
        s8 ah = *(const s8*)(ldsH + m * 136 + ks2 * 32 + q * 8);
        acc2 = __builtin_amdgcn_mfma_f32_16x16x32_bf16(ah, bw, acc2, 0, 0, 0);
    }

    // ---- layer 3 + logsigmoid + per-t mask ----
    float* ldsPart = (float*)(smem + PRT_OFF);   // [2][32]
    v4f zv;
#pragma unroll
    for (int reg = 0; reg < 4; ++reg)
        zv[reg] = fmaxf(acc2[reg] + b2v, 0.0f) * w3v;
#pragma unroll
    for (int msk = 1; msk < 16; msk <<= 1) {
#pragma unroll
        for (int reg = 0; reg < 4; ++reg)
            zv[reg] += __shfl_xor(zv[reg], msk, 16);
    }
    if (m == 0) {
#pragma unroll
        for (int reg = 0; reg < 4; ++reg) {
            int bC = ((w & 1) << 4) + q * 4 + reg;
            int lenC = is64 ? lenp[2 * bC] : lenp[bC];
            float logit = zv[reg] + b3s;
            float logp  = fminf(logit, 0.0f) - log1pf(__expf(-fabsf(logit)));
            ldsPart[(w >> 1) * 32 + bC] = (tA < lenC) ? logp : 0.0f;
        }
    }
    __syncthreads();
    if (tid < 32)
        partials[tid * NBLK + blk] = ldsPart[tid] + ldsPart[32 + tid];
}

// ---------------- kernel 2: reduce + exp ----------------
__global__ void finalize(const float* __restrict__ partials,
                         float* __restrict__ out) {
    const int b = blockIdx.x;
    const int tid = threadIdx.x;
    float s = 0.0f;
    for (int i = tid; i < NBLK; i += 256) s += partials[b * NBLK + i];
#pragma unroll
    for (int off = 32; off > 0; off >>= 1) s += __shfl_down(s, off, 64);
    __shared__ float red[4];
    if ((tid & 63) == 0) red[tid >> 6] = s;
    __syncthreads();
    if (tid == 0) out[b] = expf(red[0] + red[1] + red[2] + red[3]);
}

extern "C" void kernel_launch(void* const* d_in, const int* in_sizes, int n_in,
                              void* d_out, int out_size, void* d_ws, size_t ws_size,
                              hipStream_t stream) {
    const float* enc = (const float*)d_in[0];
    const int*   len = (const int*)d_in[1];
    const float* W1  = (const float*)d_in[2];
    const float* b1  = (const float*)d_in[3];
    const float* W2  = (const float*)d_in[4];
    const float* b2  = (const float*)d_in[5];
    const float* W3  = (const float*)d_in[6];
    const float* b3  = (const float*)d_in[7];

    unsigned short* wsb = (unsigned short*)d_ws;
    float* partials = (float*)((char*)d_ws + PART_OFF_BYTES);
    float* out = (float*)d_out;

    convert_weights<<<57, 256, 0, stream>>>(W1, W2, wsb);
    mlp_main<<<NBLK, 256, 0, stream>>>(enc, len, b1, b2, W3, b3,
                                       wsb, wsb + W1P_ELEMS, partials);
    finalize<<<32, 256, 0, stream>>>(partials, out);
}